// Round 6
// baseline (37.216 us; speedup 1.0000x reference)
//
#include <hip/hip_runtime.h>
#include <hip/hip_bf16.h>

// ParallelCheby2D via MFMA (layout-robust formulation, proven correct R5).
// out[b,t] = Re( sum_i x[t-i] * g_i ),  g_i = sum_j C_i^T W_{4i+j} C_j,
//   C_d[q] = T_q(|x[t-d]|).
// Heavy part: U = M x Y per component, M[8i+p][8j+q] = w[4i+j][p][q] (32x32),
// K=32 split into two v_mfma_f32_32x32x16_bf16. Both A and B slots (s,hi,e)
// carry the SAME feature f = 8*(2s+hi)+e -> correct under any HW k-mapping.
// D layout (HW-measured): col=lane&31, row=(reg&3)+8*(reg>>2)+4*hi.
//
// R6 changes (latency, not math): LDS-staged x taps (one coalesced burst per
// block instead of 8 scalar HBM loads per round on the critical path) and
// grid sized to exactly fill the machine: 2048 blocks x 4 waves = 8192 waves
// = 8 waves/SIMD = 100% occupancy, single generation.

typedef __attribute__((ext_vector_type(8))) short bf16x8;   // 8 bf16 = 4 VGPRs
typedef __attribute__((ext_vector_type(16))) float f32x16;  // 16 f32 accum

static constexpr int T_LEN  = 131072;  // 2^17
static constexpr int ROUNDS = 2;       // 32 samples per wave per round
static constexpr int SPB    = 256;     // samples per block = 4 waves * ROUNDS * 32

union FragU { short s[8]; bf16x8 v; };

__device__ inline short f2bf(float f) {
    union { __hip_bfloat16 h; unsigned short u; } cv;
    cv.h = __float2bfloat16(f);   // RNE
    return (short)cv.u;
}

__global__ __launch_bounds__(256, 4) void cheby2d_mfma(
    const float* __restrict__ xr_g, const float* __restrict__ xi_g,
    const float* __restrict__ wr_g, const float* __restrict__ wi_g,
    float* __restrict__ out)
{
    __shared__ float xr_s[SPB + 4];   // [0..2] = 3-tap head, [3+s] = sample s
    __shared__ float xi_s[SPB + 4];

    const int tid  = threadIdx.x;
    const int lane = tid & 63;
    const int wid  = tid >> 6;    // wave in block (0..3)
    const int col  = lane & 31;   // sample slot / A row (8i+p)
    const int hi   = lane >> 5;   // lane half -> k-half slot AND Cheby row owner
    const int row  = col;

    const int base   = blockIdx.x * SPB;
    const int t_base = base & (T_LEN - 1);   // multiple of SPB; 0 <=> batch-row start

    // ---- stage x span into LDS (fully coalesced, one touch per line) ----
    xr_s[3 + tid] = xr_g[base + tid];
    xi_s[3 + tid] = xi_g[base + tid];
    if (tid < 3) {
        const bool head_ok = (t_base != 0);  // zero-pad at batch-row start
        xr_s[tid] = head_ok ? xr_g[base - 3 + tid] : 0.f;
        xi_s[tid] = head_ok ? xi_g[base - 3 + tid] : 0.f;
    }

    // ---- A fragments (constant weights), once per wave; overlaps staging ----
    // slot (s,hi,e) <- M[row][f=8*(2s+hi)+e] = w[4*(row>>3)+(2s+hi)][row&7][e]
    bf16x8 aR[2], aI[2];
#pragma unroll
    for (int s = 0; s < 2; ++s) {
        const int br = 4 * (row >> 3) + 2 * s + hi;
        const float* pr = wr_g + br * 64 + (row & 7) * 8;
        const float* pi = wi_g + br * 64 + (row & 7) * 8;
        FragU fr, fi;
#pragma unroll
        for (int e = 0; e < 8; ++e) { fr.s[e] = f2bf(pr[e]); fi.s[e] = f2bf(pi[e]); }
        aR[s] = fr.v; aI[s] = fi.v;
    }

    // Persistent zero tile as C-in of each chain head.
    f32x16 zacc;
#pragma unroll
    for (int r = 0; r < 16; ++r) zacc[r] = 0.f;

    __syncthreads();

#pragma unroll
    for (int rd = 0; rd < ROUNDS; ++rd) {
        const int local = (wid * ROUNDS + rd) * 32 + col;  // 0..SPB-1
        const int idx   = base + local;

        // ---- taps from LDS (conflict-free stride-1), magnitudes, Cheby ----
        float xr[4], xi[4], C[4][8];
#pragma unroll
        for (int d = 0; d < 4; ++d) {
            const float a = xr_s[3 + local - d];
            const float b = xi_s[3 + local - d];
            xr[d] = a; xi[d] = b;
            const float r = sqrtf(fmaf(a, a, b * b));
            C[d][0] = 1.f;
            C[d][1] = r;
            const float r2 = r + r;
#pragma unroll
            for (int q = 2; q < 8; ++q)
                C[d][q] = fmaf(r2, C[d][q - 1], -C[d][q - 2]);
        }

        // ---- B fragments, purely lane-local (ternary -> cndmask) ----
        FragU b0, b1;
#pragma unroll
        for (int e = 0; e < 8; ++e) {
            b0.s[e] = f2bf(hi ? C[1][e] : C[0][e]);
            b1.s[e] = f2bf(hi ? C[3][e] : C[2][e]);
        }

        // ---- U = M x Y, both components (two independent 2-chains) ----
        f32x16 accR = __builtin_amdgcn_mfma_f32_32x32x16_bf16(aR[0], b0.v, zacc, 0, 0, 0);
        accR        = __builtin_amdgcn_mfma_f32_32x32x16_bf16(aR[1], b1.v, accR, 0, 0, 0);
        f32x16 accI = __builtin_amdgcn_mfma_f32_32x32x16_bf16(aI[0], b0.v, zacc, 0, 0, 0);
        accI        = __builtin_amdgcn_mfma_f32_32x32x16_bf16(aI[1], b1.v, accI, 0, 0, 0);

        // ---- epilogue: acc[4i+r] = U[i][p=r+4*hi] for sample col ----
        float o = 0.f;
#pragma unroll
        for (int i = 0; i < 4; ++i) {
            float gr = 0.f, gi = 0.f;
#pragma unroll
            for (int r = 0; r < 4; ++r) {
                const float cip = hi ? C[i][4 + r] : C[i][r];
                gr = fmaf(cip, accR[4 * i + r], gr);
                gi = fmaf(cip, accI[4 * i + r], gi);
            }
            o = fmaf(xr[i], gr, o);
            o = fmaf(-xi[i], gi, o);
        }

        // Combine p-halves across lane halves; store from low half.
        o += __shfl_xor(o, 32);
        if (hi == 0) out[idx] = o;
    }
}

extern "C" void kernel_launch(void* const* d_in, const int* in_sizes, int n_in,
                              void* d_out, int out_size, void* d_ws, size_t ws_size,
                              hipStream_t stream) {
    const float* xr = (const float*)d_in[0];  // [B,1,T] float32
    const float* xi = (const float*)d_in[1];  // [B,1,T] float32
    const float* wr = (const float*)d_in[2];  // [16,8,8] float32
    const float* wi = (const float*)d_in[3];  // [16,8,8] float32
    float* out = (float*)d_out;               // [B,T] real part, float32

    const int total  = in_sizes[0];           // 524288
    const int blocks = total / SPB;           // 2048 -> 8192 waves = 8/SIMD
    cheby2d_mfma<<<blocks, 256, 0, stream>>>(xr, xi, wr, wi, out);
}